// Round 1
// baseline (242.937 us; speedup 1.0000x reference)
//
#include <hip/hip_runtime.h>
#include <math.h>

// Problem constants (B=4, S=8192, D=1024, DG=256, E=64, K=2)
#define NTOK   32768   // B*S
#define DMODEL 1024
#define NEXP   64
#define DGENRE 256
#define BK     64      // K-chunk staged in LDS
#define TT     64      // tokens per block
#define XSTR   68      // padded token-stride of transposed x tile (17*16B -> aligned b128, bank-rotated)

// ---- kernel 1: c[b][e] = bias[e] + genre[b,:] @ Wg[:,e]  (tiny: 256 outputs) ----
__global__ void genre_bias_k(const float* __restrict__ genre,
                             const float* __restrict__ Wg,
                             const float* __restrict__ bias,
                             float* __restrict__ c) {
  int tid = threadIdx.x;          // 256 threads, 1 block
  int b = tid >> 6, e = tid & 63;
  float acc = bias[e];
  const float* g = genre + b * DGENRE;
  for (int d = 0; d < DGENRE; ++d) acc = fmaf(g[d], Wg[d * NEXP + e], acc);
  c[b * NEXP + e] = acc;
}

// jax.lax.top_k order: value descending, ties -> lower index first
__device__ __forceinline__ bool better(float va, int ia, float vb, int ib) {
  return (va > vb) || (va == vb && ia < ib);
}

// ---- kernel 2: fused logits GEMM + top-2 softmax gate ----
__global__ __launch_bounds__(256, 2) void moe_gate_k(
    const float* __restrict__ x, const float* __restrict__ Wx,
    const float* __restrict__ c, float* __restrict__ out) {
  __shared__ float xs[BK][XSTR];    // x tile, TRANSPOSED: [d][token]
  __shared__ float wss[BK][NEXP];   // Wx tile: [d][expert]

  const int tid  = threadIdx.x;
  const int tok0 = blockIdx.x * TT;

  // compute mapping: thread owns 4 tokens x 4 experts
  const int eg = tid & 15;          // expert group (lane bits 0..3 -> shuffle group)
  const int tg = tid >> 4;          // token group
  const int e0 = eg * 4;
  const int t0 = tg * 4;

  // load mapping: lq = column-quad (coalesced along fastest dim), lr = row
  const int lq = tid & 15;
  const int lr = tid >> 4;

  float acc[4][4] = {{0.f}};

  for (int d0 = 0; d0 < DMODEL; d0 += BK) {
    __syncthreads();
    // x[token][d0+lq*4 ..+3] -> transposed scatter into xs[d][token]
#pragma unroll
    for (int l = 0; l < 4; ++l) {
      int t = lr + l * 16;
      float4 v = *reinterpret_cast<const float4*>(
          &x[(size_t)(tok0 + t) * DMODEL + d0 + lq * 4]);
      xs[lq * 4 + 0][t] = v.x;
      xs[lq * 4 + 1][t] = v.y;
      xs[lq * 4 + 2][t] = v.z;
      xs[lq * 4 + 3][t] = v.w;
    }
    // Wx[d0+r][lq*4 ..+3] -> wss[r][e] (row-major, b128 in/out)
#pragma unroll
    for (int l = 0; l < 4; ++l) {
      int r = lr + l * 16;
      *reinterpret_cast<float4*>(&wss[r][lq * 4]) =
          *reinterpret_cast<const float4*>(&Wx[(size_t)(d0 + r) * NEXP + lq * 4]);
    }
    __syncthreads();
#pragma unroll 8
    for (int d = 0; d < BK; ++d) {
      float4 xv = *reinterpret_cast<const float4*>(&xs[d][t0]);   // 4 tokens
      float4 wv = *reinterpret_cast<const float4*>(&wss[d][e0]);  // 4 experts
      float xa[4] = {xv.x, xv.y, xv.z, xv.w};
      float wa[4] = {wv.x, wv.y, wv.z, wv.w};
#pragma unroll
      for (int i = 0; i < 4; ++i)
#pragma unroll
        for (int j = 0; j < 4; ++j)
          acc[i][j] = fmaf(xa[i], wa[j], acc[i][j]);
    }
  }

  // add genre/bias term (depends on batch and expert only)
  const int b = tok0 >> 13;   // tok0/8192; TT=64 divides S -> tile never straddles batch
#pragma unroll
  for (int j = 0; j < 4; ++j) {
    float cb = c[b * NEXP + e0 + j];
#pragma unroll
    for (int i = 0; i < 4; ++i) acc[i][j] += cb;
  }

  float* gates  = out;
  float* idxout = out + (size_t)NTOK * NEXP;  // topk_idx written as float values

#pragma unroll
  for (int i = 0; i < 4; ++i) {
    // lane-local top-2 of this thread's 4 experts
    float v1 = acc[i][0]; int i1 = e0;
    float v2 = -INFINITY; int i2 = NEXP;
#pragma unroll
    for (int j = 1; j < 4; ++j) {
      float a = acc[i][j]; int ei = e0 + j;
      if (better(a, ei, v1, i1)) { v2 = v1; i2 = i1; v1 = a; i1 = ei; }
      else if (better(a, ei, v2, i2)) { v2 = a; i2 = ei; }
    }
    // butterfly merge across the 16 lanes holding this token's 64 experts
#pragma unroll
    for (int m = 1; m < 16; m <<= 1) {
      float ov1 = __shfl_xor(v1, m, 64); int oi1 = __shfl_xor(i1, m, 64);
      float ov2 = __shfl_xor(v2, m, 64); int oi2 = __shfl_xor(i2, m, 64);
      if (better(v1, i1, ov1, oi1)) {
        if (better(ov1, oi1, v2, i2)) { v2 = ov1; i2 = oi1; }
      } else {
        if (better(v1, i1, ov2, oi2)) { v2 = v1; i2 = i1; }
        else                          { v2 = ov2; i2 = oi2; }
        v1 = ov1; i1 = oi1;
      }
    }
    // renormalized top-2 softmax weights: p1/(p1+p2) = 1/(1+exp(l2-l1))
    float ew  = expf(v2 - v1);
    float inv = 1.0f / (1.0f + ew);
    float w1 = inv, w2 = ew * inv;

    int tok = tok0 + t0 + i;
    float4 g;
    g.x = (e0 + 0 == i1) ? w1 : ((e0 + 0 == i2) ? w2 : 0.0f);
    g.y = (e0 + 1 == i1) ? w1 : ((e0 + 1 == i2) ? w2 : 0.0f);
    g.z = (e0 + 2 == i1) ? w1 : ((e0 + 2 == i2) ? w2 : 0.0f);
    g.w = (e0 + 3 == i1) ? w1 : ((e0 + 3 == i2) ? w2 : 0.0f);
    *reinterpret_cast<float4*>(&gates[(size_t)tok * NEXP + e0]) = g;

    if (eg == 0) {
      idxout[(size_t)tok * 2 + 0] = (float)i1;
      idxout[(size_t)tok * 2 + 1] = (float)i2;
    }
  }
}

extern "C" void kernel_launch(void* const* d_in, const int* in_sizes, int n_in,
                              void* d_out, int out_size, void* d_ws, size_t ws_size,
                              hipStream_t stream) {
  const float* x     = (const float*)d_in[0];
  const float* genre = (const float*)d_in[1];
  const float* Wx    = (const float*)d_in[2];
  const float* Wg    = (const float*)d_in[3];
  const float* bias  = (const float*)d_in[4];
  float* out = (float*)d_out;
  float* c   = (float*)d_ws;   // 256 floats of scratch

  genre_bias_k<<<1, 256, 0, stream>>>(genre, Wg, bias, c);
  moe_gate_k<<<NTOK / TT, 256, 0, stream>>>(x, Wx, c, out);
}

// Round 4
// 222.597 us; speedup vs baseline: 1.0914x; 1.0914x over previous
//
#include <hip/hip_runtime.h>
#include <math.h>

// Problem constants (B=4, S=8192, D=1024, DG=256, E=64, K=2)
#define NTOK   32768   // B*S
#define DMODEL 1024
#define NEXP   64
#define DGENRE 256
#define BK     64      // d-chunk staged in LDS
#define TT     64      // tokens per block

// address-space types for global_load_lds
typedef const __attribute__((address_space(1))) void ga_void;
typedef __attribute__((address_space(3))) void lds_void;

// jax.lax.top_k order: value descending, ties -> lower index first
__device__ __forceinline__ bool better(float va, int ia, float vb, int ib) {
  return (va > vb) || (va == vb && ia < ib);
}

// Fused: genre bias + logits GEMM + top-2 softmax gate.
// Block: 64 tokens x 64 experts, 256 threads, thread tile 4 tok x 4 exp.
// xs layout: [t][d] linear (global_load_lds needs linear dest), with the
// 16B quad index XOR-swizzled by (t>>2)&3 via the PRE-SWIZZLED GLOBAL source
// (rule: both-sides-or-neither). Read banks: 4*((dq^tg)&7) -> conflict-free.
__global__ __launch_bounds__(256, 2) void moe_gate_k(
    const float* __restrict__ x, const float* __restrict__ Wx,
    const float* __restrict__ genre, const float* __restrict__ Wg,
    const float* __restrict__ bias, float* __restrict__ out) {
  __shared__ __align__(16) float xs[2][TT * BK];    // 2 x 16 KB
  __shared__ __align__(16) float ws[2][BK * NEXP];  // 2 x 16 KB
  __shared__ float cpart[4][NEXP];
  __shared__ float cbias[NEXP];

  const int tid  = threadIdx.x;
  const int wv   = tid >> 6;        // wave 0..3
  const int lane = tid & 63;
  const int tok0 = blockIdx.x * TT;
  const int b    = tok0 >> 13;      // tok0 / 8192; TT divides S

  // ---- inline genre bias: cbias[e] = bias[e] + genre[b,:] . Wg[:,e] ----
  {
    const int e = tid & 63, dc = tid >> 6;
    const float* g  = genre + b * DGENRE + dc * 64;
    const float* wg = Wg + (size_t)(dc * 64) * NEXP + e;
    float p = 0.f;
#pragma unroll 8
    for (int d = 0; d < 64; ++d) p = fmaf(g[d], wg[(size_t)d * NEXP], p);
    cpart[dc][e] = p;
  }

  // compute mapping: thread = 4 tokens x 4 experts
  const int eg = tid & 15;          // expert group (16 lanes per token set)
  const int tg = tid >> 4;          // token group 0..15
  const int e0 = eg * 4;
  const int t0 = tg * 4;
  const int sw = tg & 3;            // xs read swizzle for this thread's tokens

  float acc[4][4] = {{0.f}};

  // ---- staging: per chunk, each wave issues 4+4 global_load_lds (16B) ----
  // xs unit L (0..1023): token t=L>>4, phys quad p=L&15, logical dq=p^((t>>2)&3)
  // ws unit L: pure linear match with Wx rows (row d=L>>4, quad q=L&15)
#define STAGE(bufidx, d0)                                                      \
  {                                                                            \
    _Pragma("unroll")                                                          \
    for (int s = 0; s < 4; ++s) {                                              \
      const int L = wv * 256 + s * 64 + lane;                                  \
      const int t = L >> 4, pq = L & 15;                                       \
      const int dq = pq ^ ((t >> 2) & 3);                                      \
      const float* gsrc = x + (size_t)(tok0 + t) * DMODEL + (d0) + dq * 4;     \
      __builtin_amdgcn_global_load_lds((ga_void*)gsrc,                         \
          (lds_void*)&xs[bufidx][(wv * 256 + s * 64) * 4], 16, 0, 0);          \
      const float* wsrc = Wx + (size_t)(d0) * NEXP + L * 4;                    \
      __builtin_amdgcn_global_load_lds((ga_void*)wsrc,                         \
          (lds_void*)&ws[bufidx][(wv * 256 + s * 64) * 4], 16, 0, 0);          \
    }                                                                          \
  }

#define COMPUTE(bufidx)                                                        \
  {                                                                            \
    const float* xb = &xs[bufidx][0];                                          \
    const float* wb = &ws[bufidx][0];                                          \
    _Pragma("unroll 4")                                                        \
    for (int dq = 0; dq < 16; ++dq) {                                          \
      float4 xv[4], wv4[4];                                                    \
      _Pragma("unroll")                                                        \
      for (int i = 0; i < 4; ++i)                                              \
        xv[i] = *reinterpret_cast<const float4*>(                              \
            &xb[(t0 + i) * BK + ((dq ^ sw) << 2)]);                            \
      _Pragma("unroll")                                                        \
      for (int dd = 0; dd < 4; ++dd)                                           \
        wv4[dd] = *reinterpret_cast<const float4*>(                            \
            &wb[(dq * 4 + dd) * NEXP + e0]);                                   \
      _Pragma("unroll")                                                        \
      for (int dd = 0; dd < 4; ++dd) {                                         \
        _Pragma("unroll")                                                      \
        for (int i = 0; i < 4; ++i) {                                          \
          const float xvv = reinterpret_cast<const float*>(&xv[i])[dd];        \
          _Pragma("unroll")                                                    \
          for (int j = 0; j < 4; ++j)                                          \
            acc[i][j] = fmaf(                                                  \
                xvv, reinterpret_cast<const float*>(&wv4[dd])[j], acc[i][j]);  \
        }                                                                      \
      }                                                                        \
    }                                                                          \
  }

  STAGE(0, 0);
  __syncthreads();  // drains staging vmcnt + covers cpart writes
  if (tid < NEXP)
    cbias[tid] = bias[tid] + cpart[0][tid] + cpart[1][tid] + cpart[2][tid] +
                 cpart[3][tid];

  for (int c = 0; c < DMODEL / BK; ++c) {
    if (c < DMODEL / BK - 1) STAGE((c + 1) & 1, (c + 1) * BK);  // issue early
    COMPUTE(c & 1);
    __syncthreads();  // waits staged loads; frees read buffer for next stage
  }

  // ---- epilogue: add bias, top-2 across 16-lane expert groups, write ----
#pragma unroll
  for (int j = 0; j < 4; ++j) {
    const float cb = cbias[e0 + j];
#pragma unroll
    for (int i = 0; i < 4; ++i) acc[i][j] += cb;
  }

  float* gates  = out;
  float* idxout = out + (size_t)NTOK * NEXP;  // topk_idx written as floats

#pragma unroll
  for (int i = 0; i < 4; ++i) {
    // lane-local top-2 of this thread's 4 experts
    float v1 = acc[i][0]; int i1 = e0;
    float v2 = -INFINITY; int i2 = NEXP;
#pragma unroll
    for (int j = 1; j < 4; ++j) {
      const float a = acc[i][j]; const int ei = e0 + j;
      if (better(a, ei, v1, i1)) { v2 = v1; i2 = i1; v1 = a; i1 = ei; }
      else if (better(a, ei, v2, i2)) { v2 = a; i2 = ei; }
    }
    // butterfly merge across the 16 lanes holding this token's 64 experts
#pragma unroll
    for (int m = 1; m < 16; m <<= 1) {
      const float ov1 = __shfl_xor(v1, m, 64); const int oi1 = __shfl_xor(i1, m, 64);
      const float ov2 = __shfl_xor(v2, m, 64); const int oi2 = __shfl_xor(i2, m, 64);
      if (better(v1, i1, ov1, oi1)) {
        if (better(ov1, oi1, v2, i2)) { v2 = ov1; i2 = oi1; }
      } else {
        if (better(v1, i1, ov2, oi2)) { v2 = v1; i2 = i1; }
        else                          { v2 = ov2; i2 = oi2; }
        v1 = ov1; i1 = oi1;
      }
    }
    // renormalized top-2 softmax weights: p1/(p1+p2) = 1/(1+exp(l2-l1))
    const float ew  = expf(v2 - v1);
    const float inv = 1.0f / (1.0f + ew);
    const float w1 = inv, w2 = ew * inv;

    const int tok = tok0 + t0 + i;
    float4 g;
    g.x = (e0 + 0 == i1) ? w1 : ((e0 + 0 == i2) ? w2 : 0.0f);
    g.y = (e0 + 1 == i1) ? w1 : ((e0 + 1 == i2) ? w2 : 0.0f);
    g.z = (e0 + 2 == i1) ? w1 : ((e0 + 2 == i2) ? w2 : 0.0f);
    g.w = (e0 + 3 == i1) ? w1 : ((e0 + 3 == i2) ? w2 : 0.0f);
    *reinterpret_cast<float4*>(&gates[(size_t)tok * NEXP + e0]) = g;

    if (eg == 0) {
      idxout[(size_t)tok * 2 + 0] = (float)i1;
      idxout[(size_t)tok * 2 + 1] = (float)i2;
    }
  }
}

extern "C" void kernel_launch(void* const* d_in, const int* in_sizes, int n_in,
                              void* d_out, int out_size, void* d_ws, size_t ws_size,
                              hipStream_t stream) {
  const float* x     = (const float*)d_in[0];
  const float* genre = (const float*)d_in[1];
  const float* Wx    = (const float*)d_in[2];
  const float* Wg    = (const float*)d_in[3];
  const float* bias  = (const float*)d_in[4];
  float* out = (float*)d_out;

  moe_gate_k<<<NTOK / TT, 256, 0, stream>>>(x, Wx, genre, Wg, bias, out);
}